// Round 3
// baseline (645.340 us; speedup 1.0000x reference)
//
#include <hip/hip_runtime.h>
#include <hip/hip_bf16.h>

// SCM_39676907888322: sigmoid-gated cross attention. fp32 I/O, bf16 MFMA compute.
// R3: attn m-split 4-way by wave (9216 waves, ~100% occupancy), NO in-loop barrier
//     (P strip is wave-private), partial-O combined via fp32 atomics into out
//     (Fu region zeroed by qkv kernel, stream-ordered). qkv n-tile 32 (1152 blocks).

typedef __bf16 bf16;
typedef __bf16 bf16x8 __attribute__((ext_vector_type(8)));
typedef __bf16 bf16x4 __attribute__((ext_vector_type(4)));
typedef float f32x4 __attribute__((ext_vector_type(4)));

#define NB 8
#define NC 256
#define NCI 128
#define NHW 2304
#define NT32 72    // 2304 / 32  (qkv n-tiles)
#define NT16 144   // 2304 / 16  (attn n-tiles)

__global__ __launch_bounds__(256) void wconv_kernel(
    const float* __restrict__ w0, const float* __restrict__ w1,
    const float* __restrict__ w2, const float* __restrict__ w3,
    const float* __restrict__ w4, const float* __restrict__ w5,
    bf16* __restrict__ dst)
{
    int idx = (blockIdx.x * 256 + threadIdx.x) * 8;   // 6*32768 total
    int m = idx >> 15;                                 // matrix id (block-uniform)
    int off = idx & 32767;
    const float* w = (m == 0) ? w0 : (m == 1) ? w1 : (m == 2) ? w2
                   : (m == 3) ? w3 : (m == 4) ? w4 : w5;
    f32x4 a0 = *(const f32x4*)(w + off);
    f32x4 a1 = *(const f32x4*)(w + off + 4);
    bf16x8 o;
    #pragma unroll
    for (int j = 0; j < 4; ++j) { o[j] = (bf16)a0[j]; o[4 + j] = (bf16)a1[j]; }
    *(bf16x8*)(dst + idx) = o;
}

__global__ __launch_bounds__(256) void qkv_kernel(
    const float* __restrict__ x1, const float* __restrict__ x2,
    const bf16* __restrict__ wb,
    const float* __restrict__ bv1, const float* __restrict__ bk1, const float* __restrict__ bq1,
    const float* __restrict__ bv2, const float* __restrict__ bk2, const float* __restrict__ bq2,
    bf16* __restrict__ Qt, bf16* __restrict__ Kt, bf16* __restrict__ Vt,
    float* __restrict__ out)
{
    // Xt[n][c] bf16, 32 rows, padded stride 264
    __shared__ __align__(16) bf16 Xt[32 * 264];

    int gid = blockIdx.x;
    int nt = gid % NT32;
    int s = (gid / NT32) & 1;
    int b = gid / (2 * NT32);
    int n0 = nt * 32;

    const float* x = s ? x2 : x1;
    // wb layout: [v1,k1,q1,v2,k2,q2] each 128*256
    const bf16* wv = wb + (size_t)(s * 3 + 0) * (NCI * NC);
    const bf16* wk = wb + (size_t)(s * 3 + 1) * (NCI * NC);
    const bf16* wq = wb + (size_t)(s * 3 + 2) * (NCI * NC);
    const float* bv = s ? bv2 : bv1;
    const float* bk = s ? bk2 : bk1;
    const float* bq = s ? bq2 : bq1;
    float* outy = out + (size_t)s * (NB * 384 * NHW);

    int tid = threadIdx.x;
    // Stage X tile (256 c x 32 n) into LDS transposed (bf16); fp32 concat passthrough.
    {
        int n_off = (tid & 3) * 8;       // 0,8,16,24
        int c0l = tid >> 2;              // 0..63
        #pragma unroll
        for (int i = 0; i < 4; ++i) {
            int c = c0l + i * 64;
            const float* src = x + ((size_t)(b * NC + c) * NHW + n0 + n_off);
            f32x4 a0 = *(const f32x4*)src;
            f32x4 a1 = *(const f32x4*)(src + 4);
            float* dsty = outy + ((size_t)(b * 384 + c) * NHW + n0 + n_off);
            *(f32x4*)dsty = a0;
            *(f32x4*)(dsty + 4) = a1;
            #pragma unroll
            for (int j = 0; j < 4; ++j) {
                Xt[(n_off + j) * 264 + c] = (bf16)a0[j];
                Xt[(n_off + 4 + j) * 264 + c] = (bf16)a1[j];
            }
        }
    }
    // Zero the Fu output region for (dir=s, b, n0..n0+31): attn atomically adds into it.
    {
        int c = tid >> 1;                // 0..127
        int nf = (tid & 1) * 16;
        float* z = outy + ((size_t)(b * 384 + 256 + c) * NHW + n0 + nf);
        f32x4 zero = (f32x4){0.f, 0.f, 0.f, 0.f};
        #pragma unroll
        for (int u = 0; u < 4; ++u) *(f32x4*)(z + u * 4) = zero;
    }
    __syncthreads();

    int lane = tid & 63;
    int wid = tid >> 6;                  // wave 0..3 -> ci strip of 32
    int row = lane & 15, quad = lane >> 4;
    int ci_base = wid * 32;

    f32x4 acc[3][2][2];                  // [q,k,v][mi][j]
    #pragma unroll
    for (int t = 0; t < 3; ++t)
        #pragma unroll
        for (int mi = 0; mi < 2; ++mi)
            #pragma unroll
            for (int j = 0; j < 2; ++j)
                acc[t][mi][j] = (f32x4){0.f, 0.f, 0.f, 0.f};

    const bf16* wptr[3] = {wq, wk, wv};
    #pragma unroll
    for (int ks = 0; ks < 8; ++ks) {
        int c0 = ks * 32 + quad * 8;
        bf16x8 bfrag[2];
        #pragma unroll
        for (int j = 0; j < 2; ++j)
            bfrag[j] = *(const bf16x8*)&Xt[(j * 16 + row) * 264 + c0];
        #pragma unroll
        for (int t = 0; t < 3; ++t) {
            #pragma unroll
            for (int mi = 0; mi < 2; ++mi) {
                bf16x8 afrag = *(const bf16x8*)&wptr[t][(size_t)(ci_base + mi * 16 + row) * NC + c0];
                #pragma unroll
                for (int j = 0; j < 2; ++j)
                    acc[t][mi][j] = __builtin_amdgcn_mfma_f32_16x16x32_bf16(
                        afrag, bfrag[j], acc[t][mi][j], 0, 0, 0);
            }
        }
    }

    // Epilogue: +bias (fp32), write Qt/Kt (n,128) bf16 8B stores, V (128,n) bf16 scalar.
    size_t qkbase = ((size_t)s * NB + b) * NHW * NCI;
    size_t vbase  = ((size_t)s * NB + b) * NCI * NHW;
    #pragma unroll
    for (int mi = 0; mi < 2; ++mi) {
        int ci0 = ci_base + mi * 16 + quad * 4;
        f32x4 bq4 = *(const f32x4*)&bq[ci0];
        f32x4 bk4 = *(const f32x4*)&bk[ci0];
        f32x4 bv4 = *(const f32x4*)&bv[ci0];
        #pragma unroll
        for (int j = 0; j < 2; ++j) {
            int n = n0 + j * 16 + row;   // D col = lane&15
            bf16x4 pk;
            #pragma unroll
            for (int r = 0; r < 4; ++r) pk[r] = (bf16)(acc[0][mi][j][r] + bq4[r]);
            *(bf16x4*)&Qt[qkbase + (size_t)n * NCI + ci0] = pk;
            #pragma unroll
            for (int r = 0; r < 4; ++r) pk[r] = (bf16)(acc[1][mi][j][r] + bk4[r]);
            *(bf16x4*)&Kt[qkbase + (size_t)n * NCI + ci0] = pk;
            #pragma unroll
            for (int r = 0; r < 4; ++r)
                Vt[vbase + (size_t)(ci0 + r) * NHW + n] = (bf16)(acc[2][mi][j][r] + bv4[r]);
        }
    }
}

__global__ __launch_bounds__(256) void attn_kernel(
    const bf16* __restrict__ Qt, const bf16* __restrict__ Kt, const bf16* __restrict__ Vt,
    float* __restrict__ out)
{
    // Per-wave private P strip: 16 rows x 64 m, padded to 72
    __shared__ __align__(16) bf16 P[4][16 * 72];

    int gid = blockIdx.x;
    int nt = gid % NT16;
    int dir = (gid / NT16) & 1;          // 0: Fu1 = sig(Q1^T K2) V2 ; 1: Fu2
    int b = gid / (2 * NT16);

    int tid = threadIdx.x;
    int lane = tid & 63, w = tid >> 6;
    int row = lane & 15, quad = lane >> 4;

    int sq = dir, skv = dir ^ 1;
    const bf16* q = Qt + ((size_t)sq  * NB + b) * (NHW * NCI);
    const bf16* k = Kt + ((size_t)skv * NB + b) * (NHW * NCI);
    const bf16* v = Vt + ((size_t)skv * NB + b) * (NCI * NHW);
    float* outy = out + (size_t)dir * (NB * 384 * NHW) + ((size_t)b * 384 + 256) * NHW;

    int nw = nt * 16;                    // this block's 16 Q rows (shared by 4 waves)
    bf16x8 qf[4];                        // Q A-frags, resident across m-loop
    #pragma unroll
    for (int ks = 0; ks < 4; ++ks)
        qf[ks] = *(const bf16x8*)&q[(size_t)(nw + row) * NCI + ks * 32 + quad * 8];

    f32x4 o[8];                          // partial O: 16 rows x 128 c over this wave's m-range
    #pragma unroll
    for (int ct = 0; ct < 8; ++ct) o[ct] = (f32x4){0.f, 0.f, 0.f, 0.f};

    bf16* Pw = P[w];
    int mbase = w * 576;                 // wave-private m-range: 9 tiles of 64

    for (int mt = 0; mt < 9; ++mt) {
        int m0 = mbase + mt * 64;
        // S = Q^T K for 16 n-rows x 64 m-cols
        f32x4 sacc[4];
        #pragma unroll
        for (int j = 0; j < 4; ++j) sacc[j] = (f32x4){0.f, 0.f, 0.f, 0.f};
        #pragma unroll
        for (int ks = 0; ks < 4; ++ks) {
            #pragma unroll
            for (int j = 0; j < 4; ++j) {
                bf16x8 kf = *(const bf16x8*)&k[(size_t)(m0 + j * 16 + row) * NCI + ks * 32 + quad * 8];
                sacc[j] = __builtin_amdgcn_mfma_f32_16x16x32_bf16(qf[ks], kf, sacc[j], 0, 0, 0);
            }
        }
        // sigmoid -> P (C/D layout -> LDS -> A-operand layout). Wave-private strip:
        // same-wave DS ordering (compiler lgkmcnt) is sufficient, NO barrier.
        #pragma unroll
        for (int j = 0; j < 4; ++j) {
            #pragma unroll
            for (int r = 0; r < 4; ++r) {
                float xv = sacc[j][r];
                float e = __expf(-xv);
                float p = __builtin_amdgcn_rcpf(1.0f + e);
                Pw[(quad * 4 + r) * 72 + j * 16 + row] = (bf16)p;
            }
        }
        // O += P * V^T  (A = P from LDS, B = V natural layout, contiguous in m)
        #pragma unroll
        for (int ks = 0; ks < 2; ++ks) {
            bf16x8 af = *(const bf16x8*)&Pw[row * 72 + ks * 32 + quad * 8];
            #pragma unroll
            for (int ct = 0; ct < 8; ++ct) {
                bf16x8 vf = *(const bf16x8*)&v[(size_t)(ct * 16 + row) * NHW + m0 + ks * 32 + quad * 8];
                o[ct] = __builtin_amdgcn_mfma_f32_16x16x32_bf16(af, vf, o[ct], 0, 0, 0);
            }
        }
    }

    // Combine partials: fp32 atomics into the (pre-zeroed) Fu region.
    int nbase = nw + quad * 4;
    #pragma unroll
    for (int ct = 0; ct < 8; ++ct) {
        int c = ct * 16 + row;
        float* dst = &outy[(size_t)c * NHW + nbase];
        #pragma unroll
        for (int r = 0; r < 4; ++r)
            unsafeAtomicAdd(dst + r, o[ct][r]);
    }
}

extern "C" void kernel_launch(void* const* d_in, const int* in_sizes, int n_in,
                              void* d_out, int out_size, void* d_ws, size_t ws_size,
                              hipStream_t stream) {
    const float* x1  = (const float*)d_in[0];
    const float* x2  = (const float*)d_in[1];
    const float* wv1 = (const float*)d_in[2];  const float* bv1 = (const float*)d_in[3];
    const float* wk1 = (const float*)d_in[4];  const float* bk1 = (const float*)d_in[5];
    const float* wq1 = (const float*)d_in[6];  const float* bq1 = (const float*)d_in[7];
    const float* wv2 = (const float*)d_in[8];  const float* bv2 = (const float*)d_in[9];
    const float* wk2 = (const float*)d_in[10]; const float* bk2 = (const float*)d_in[11];
    const float* wq2 = (const float*)d_in[12]; const float* bq2 = (const float*)d_in[13];
    float* out = (float*)d_out;

    // ws layout (bf16): Qt[2][B][2304][128] | Kt | Vt[2][B][128][2304] | wb[6][128*256]
    size_t per = (size_t)2 * NB * NHW * NCI;
    bf16* Qt = (bf16*)d_ws;
    bf16* Kt = Qt + per;
    bf16* Vt = Kt + per;
    bf16* wb = Vt + per;

    wconv_kernel<<<dim3(96), dim3(256), 0, stream>>>(wv1, wk1, wq1, wv2, wk2, wq2, wb);

    qkv_kernel<<<dim3(NB * 2 * NT32), dim3(256), 0, stream>>>(
        x1, x2, wb, bv1, bk1, bq1, bv2, bk2, bq2, Qt, Kt, Vt, out);

    attn_kernel<<<dim3(NB * 2 * NT16), dim3(256), 0, stream>>>(Qt, Kt, Vt, out);
}

// Round 4
// 246.426 us; speedup vs baseline: 2.6188x; 2.6188x over previous
//
#include <hip/hip_runtime.h>
#include <hip/hip_bf16.h>

// SCM_39676907888322: sigmoid-gated cross attention. fp32 I/O, bf16 MFMA compute.
// R4: attn rewritten — per-block cooperative LDS staging of K/V tiles (register
//     double-buffered prefetch), XCD-aware swizzle so each (b,dir) pair's K/V
//     stays in one XCD's L2, no atomics (block owns its 64-row output tile).

typedef __bf16 bf16;
typedef __bf16 bf16x8 __attribute__((ext_vector_type(8)));
typedef __bf16 bf16x4 __attribute__((ext_vector_type(4)));
typedef float f32x4 __attribute__((ext_vector_type(4)));

#define NB 8
#define NC 256
#define NCI 128
#define NHW 2304
#define NT32 72    // 2304 / 32  (qkv n-tiles)
#define KPAD 136   // K-tile LDS row stride (64 rows x 128 c)
#define VPAD 72    // V-tile LDS row stride (128 rows x 64 m)

__global__ __launch_bounds__(256) void wconv_kernel(
    const float* __restrict__ w0, const float* __restrict__ w1,
    const float* __restrict__ w2, const float* __restrict__ w3,
    const float* __restrict__ w4, const float* __restrict__ w5,
    bf16* __restrict__ dst)
{
    int idx = (blockIdx.x * 256 + threadIdx.x) * 8;   // 6*32768 total
    int m = idx >> 15;                                 // matrix id (block-uniform)
    int off = idx & 32767;
    const float* w = (m == 0) ? w0 : (m == 1) ? w1 : (m == 2) ? w2
                   : (m == 3) ? w3 : (m == 4) ? w4 : w5;
    f32x4 a0 = *(const f32x4*)(w + off);
    f32x4 a1 = *(const f32x4*)(w + off + 4);
    bf16x8 o;
    #pragma unroll
    for (int j = 0; j < 4; ++j) { o[j] = (bf16)a0[j]; o[4 + j] = (bf16)a1[j]; }
    *(bf16x8*)(dst + idx) = o;
}

__global__ __launch_bounds__(256) void qkv_kernel(
    const float* __restrict__ x1, const float* __restrict__ x2,
    const bf16* __restrict__ wb,
    const float* __restrict__ bv1, const float* __restrict__ bk1, const float* __restrict__ bq1,
    const float* __restrict__ bv2, const float* __restrict__ bk2, const float* __restrict__ bq2,
    bf16* __restrict__ Qt, bf16* __restrict__ Kt, bf16* __restrict__ Vt,
    float* __restrict__ out)
{
    // Xt[n][c] bf16, 32 rows, padded stride 264
    __shared__ __align__(16) bf16 Xt[32 * 264];

    int gid = blockIdx.x;
    int nt = gid % NT32;
    int s = (gid / NT32) & 1;
    int b = gid / (2 * NT32);
    int n0 = nt * 32;

    const float* x = s ? x2 : x1;
    // wb layout: [v1,k1,q1,v2,k2,q2] each 128*256
    const bf16* wv = wb + (size_t)(s * 3 + 0) * (NCI * NC);
    const bf16* wk = wb + (size_t)(s * 3 + 1) * (NCI * NC);
    const bf16* wq = wb + (size_t)(s * 3 + 2) * (NCI * NC);
    const float* bv = s ? bv2 : bv1;
    const float* bk = s ? bk2 : bk1;
    const float* bq = s ? bq2 : bq1;
    float* outy = out + (size_t)s * (NB * 384 * NHW);

    int tid = threadIdx.x;
    // Stage X tile (256 c x 32 n) into LDS transposed (bf16); fp32 concat passthrough.
    {
        int n_off = (tid & 3) * 8;       // 0,8,16,24
        int c0l = tid >> 2;              // 0..63
        #pragma unroll
        for (int i = 0; i < 4; ++i) {
            int c = c0l + i * 64;
            const float* src = x + ((size_t)(b * NC + c) * NHW + n0 + n_off);
            f32x4 a0 = *(const f32x4*)src;
            f32x4 a1 = *(const f32x4*)(src + 4);
            float* dsty = outy + ((size_t)(b * 384 + c) * NHW + n0 + n_off);
            *(f32x4*)dsty = a0;
            *(f32x4*)(dsty + 4) = a1;
            #pragma unroll
            for (int j = 0; j < 4; ++j) {
                Xt[(n_off + j) * 264 + c] = (bf16)a0[j];
                Xt[(n_off + 4 + j) * 264 + c] = (bf16)a1[j];
            }
        }
    }
    __syncthreads();

    int lane = tid & 63;
    int wid = tid >> 6;                  // wave 0..3 -> ci strip of 32
    int row = lane & 15, quad = lane >> 4;
    int ci_base = wid * 32;

    f32x4 acc[3][2][2];                  // [q,k,v][mi][j]
    #pragma unroll
    for (int t = 0; t < 3; ++t)
        #pragma unroll
        for (int mi = 0; mi < 2; ++mi)
            #pragma unroll
            for (int j = 0; j < 2; ++j)
                acc[t][mi][j] = (f32x4){0.f, 0.f, 0.f, 0.f};

    const bf16* wptr[3] = {wq, wk, wv};
    #pragma unroll
    for (int ks = 0; ks < 8; ++ks) {
        int c0 = ks * 32 + quad * 8;
        bf16x8 bfrag[2];
        #pragma unroll
        for (int j = 0; j < 2; ++j)
            bfrag[j] = *(const bf16x8*)&Xt[(j * 16 + row) * 264 + c0];
        #pragma unroll
        for (int t = 0; t < 3; ++t) {
            #pragma unroll
            for (int mi = 0; mi < 2; ++mi) {
                bf16x8 afrag = *(const bf16x8*)&wptr[t][(size_t)(ci_base + mi * 16 + row) * NC + c0];
                #pragma unroll
                for (int j = 0; j < 2; ++j)
                    acc[t][mi][j] = __builtin_amdgcn_mfma_f32_16x16x32_bf16(
                        afrag, bfrag[j], acc[t][mi][j], 0, 0, 0);
            }
        }
    }

    // Epilogue: +bias (fp32), write Qt/Kt (n,128) bf16 8B stores, V (128,n) bf16 scalar.
    size_t qkbase = ((size_t)s * NB + b) * NHW * NCI;
    size_t vbase  = ((size_t)s * NB + b) * NCI * NHW;
    #pragma unroll
    for (int mi = 0; mi < 2; ++mi) {
        int ci0 = ci_base + mi * 16 + quad * 4;
        f32x4 bq4 = *(const f32x4*)&bq[ci0];
        f32x4 bk4 = *(const f32x4*)&bk[ci0];
        f32x4 bv4 = *(const f32x4*)&bv[ci0];
        #pragma unroll
        for (int j = 0; j < 2; ++j) {
            int n = n0 + j * 16 + row;   // D col = lane&15
            bf16x4 pk;
            #pragma unroll
            for (int r = 0; r < 4; ++r) pk[r] = (bf16)(acc[0][mi][j][r] + bq4[r]);
            *(bf16x4*)&Qt[qkbase + (size_t)n * NCI + ci0] = pk;
            #pragma unroll
            for (int r = 0; r < 4; ++r) pk[r] = (bf16)(acc[1][mi][j][r] + bk4[r]);
            *(bf16x4*)&Kt[qkbase + (size_t)n * NCI + ci0] = pk;
            #pragma unroll
            for (int r = 0; r < 4; ++r)
                Vt[vbase + (size_t)(ci0 + r) * NHW + n] = (bf16)(acc[2][mi][j][r] + bv4[r]);
        }
    }
}

__global__ __launch_bounds__(256) void attn_kernel(
    const bf16* __restrict__ Qt, const bf16* __restrict__ Kt, const bf16* __restrict__ Vt,
    float* __restrict__ out)
{
    __shared__ __align__(16) bf16 KT[64 * KPAD];   // K-tile: [n-row 64][c 128], pad 136
    __shared__ __align__(16) bf16 VT[128 * VPAD];  // V-tile: [c 128][m 64], pad 72
    __shared__ __align__(16) bf16 P[4][16 * 72];   // per-wave P strips

    int gid = blockIdx.x;
    // XCD swizzle: gid%8 = XCD slot; pairs (b,dir0),(b,dir1) with b = gid%8 share an XCD.
    int pair = (gid & 7) * 2 + ((gid >> 3) & 1);   // 0..15
    int nt = gid >> 4;                              // 0..35
    int dir = pair & 1;
    int b = pair >> 1;
    int n0 = nt * 64;

    int tid = threadIdx.x;
    int lane = tid & 63, w = tid >> 6;
    int row = lane & 15, quad = lane >> 4;

    int sq = dir, skv = dir ^ 1;
    const bf16* q = Qt + ((size_t)sq  * NB + b) * (NHW * NCI);
    const bf16* k = Kt + ((size_t)skv * NB + b) * (NHW * NCI);
    const bf16* v = Vt + ((size_t)skv * NB + b) * (NCI * NHW);
    float* outy = out + (size_t)dir * (NB * 384 * NHW) + ((size_t)b * 384 + 256) * NHW;

    // Per-thread staging slots: 4 K-chunks + 4 V-chunks of 16B each.
    int kgoff[4], vgoff[4];
    bf16 *klp[4], *vlp[4];
    #pragma unroll
    for (int i = 0; i < 4; ++i) {
        int c = tid + i * 256;
        int kr = c >> 4, kc = c & 15;    // K: 64 rows x 16 chunks
        kgoff[i] = kr * NCI + kc * 8;
        klp[i] = &KT[kr * KPAD + kc * 8];
        int vr = c >> 3, vc = c & 7;     // V: 128 rows x 8 chunks
        vgoff[i] = vr * NHW + vc * 8;
        vlp[i] = &VT[vr * VPAD + vc * 8];
    }

    int nw = n0 + w * 16;                // this wave's 16 Q rows
    bf16x8 qf[4];                        // Q A-frags, resident across m-loop
    #pragma unroll
    for (int ks = 0; ks < 4; ++ks)
        qf[ks] = *(const bf16x8*)&q[(size_t)(nw + row) * NCI + ks * 32 + quad * 8];

    f32x4 o[8];                          // O acc: 16 rows x 128 c
    #pragma unroll
    for (int ct = 0; ct < 8; ++ct) o[ct] = (f32x4){0.f, 0.f, 0.f, 0.f};

    bf16* Pw = P[w];

    // Prefetch tile 0 into registers.
    bf16x8 kreg[4], vreg[4];
    #pragma unroll
    for (int i = 0; i < 4; ++i) {
        kreg[i] = *(const bf16x8*)(k + kgoff[i]);
        vreg[i] = *(const bf16x8*)(v + vgoff[i]);
    }

    for (int mt = 0; mt < 36; ++mt) {
        __syncthreads();                 // prior tile's LDS reads complete
        #pragma unroll
        for (int i = 0; i < 4; ++i) {
            *(bf16x8*)klp[i] = kreg[i];
            *(bf16x8*)vlp[i] = vreg[i];
        }
        __syncthreads();                 // tile mt visible to all waves
        if (mt < 35) {                   // issue prefetch for mt+1; waited on at next ds_write
            size_t ko = (size_t)(mt + 1) * 64 * NCI;
            int vo = (mt + 1) * 64;
            #pragma unroll
            for (int i = 0; i < 4; ++i) {
                kreg[i] = *(const bf16x8*)(k + ko + kgoff[i]);
                vreg[i] = *(const bf16x8*)(v + vo + vgoff[i]);
            }
        }
        // S = Q^T K for 16 n-rows x 64 m-cols (K from LDS)
        f32x4 sacc[4];
        #pragma unroll
        for (int j = 0; j < 4; ++j) sacc[j] = (f32x4){0.f, 0.f, 0.f, 0.f};
        #pragma unroll
        for (int ks = 0; ks < 4; ++ks) {
            #pragma unroll
            for (int j = 0; j < 4; ++j) {
                bf16x8 kf = *(const bf16x8*)&KT[(j * 16 + row) * KPAD + ks * 32 + quad * 8];
                sacc[j] = __builtin_amdgcn_mfma_f32_16x16x32_bf16(qf[ks], kf, sacc[j], 0, 0, 0);
            }
        }
        // sigmoid -> P (wave-private strip, same-wave DS ordering, no barrier)
        #pragma unroll
        for (int j = 0; j < 4; ++j) {
            #pragma unroll
            for (int r = 0; r < 4; ++r) {
                float xv = sacc[j][r];
                float e = __expf(-xv);
                float p = __builtin_amdgcn_rcpf(1.0f + e);
                Pw[(quad * 4 + r) * 72 + j * 16 + row] = (bf16)p;
            }
        }
        // O += P * V^T (V from LDS)
        #pragma unroll
        for (int ks = 0; ks < 2; ++ks) {
            bf16x8 af = *(const bf16x8*)&Pw[row * 72 + ks * 32 + quad * 8];
            #pragma unroll
            for (int ct = 0; ct < 8; ++ct) {
                bf16x8 vf = *(const bf16x8*)&VT[(ct * 16 + row) * VPAD + ks * 32 + quad * 8];
                o[ct] = __builtin_amdgcn_mfma_f32_16x16x32_bf16(af, vf, o[ct], 0, 0, 0);
            }
        }
    }

    // Write Fu (fp32): D col = c, rows = 4 consecutive n -> 16B stores
    int nbase = nw + quad * 4;
    #pragma unroll
    for (int ct = 0; ct < 8; ++ct) {
        int c = ct * 16 + row;
        *(f32x4*)&outy[(size_t)c * NHW + nbase] = o[ct];
    }
}

extern "C" void kernel_launch(void* const* d_in, const int* in_sizes, int n_in,
                              void* d_out, int out_size, void* d_ws, size_t ws_size,
                              hipStream_t stream) {
    const float* x1  = (const float*)d_in[0];
    const float* x2  = (const float*)d_in[1];
    const float* wv1 = (const float*)d_in[2];  const float* bv1 = (const float*)d_in[3];
    const float* wk1 = (const float*)d_in[4];  const float* bk1 = (const float*)d_in[5];
    const float* wq1 = (const float*)d_in[6];  const float* bq1 = (const float*)d_in[7];
    const float* wv2 = (const float*)d_in[8];  const float* bv2 = (const float*)d_in[9];
    const float* wk2 = (const float*)d_in[10]; const float* bk2 = (const float*)d_in[11];
    const float* wq2 = (const float*)d_in[12]; const float* bq2 = (const float*)d_in[13];
    float* out = (float*)d_out;

    // ws layout (bf16): Qt[2][B][2304][128] | Kt | Vt[2][B][128][2304] | wb[6][128*256]
    size_t per = (size_t)2 * NB * NHW * NCI;
    bf16* Qt = (bf16*)d_ws;
    bf16* Kt = Qt + per;
    bf16* Vt = Kt + per;
    bf16* wb = Vt + per;

    wconv_kernel<<<dim3(96), dim3(256), 0, stream>>>(wv1, wk1, wq1, wv2, wk2, wq2, wb);

    qkv_kernel<<<dim3(NB * 2 * NT32), dim3(256), 0, stream>>>(
        x1, x2, wb, bv1, bk1, bq1, bv2, bk2, bq2, Qt, Kt, Vt, out);

    attn_kernel<<<dim3(NB * 2 * 36), dim3(256), 0, stream>>>(Qt, Kt, Vt, out);
}